// Round 3
// baseline (421.197 us; speedup 1.0000x reference)
//
#include <hip/hip_runtime.h>
#include <math.h>

#define NN 15          // nodes
#define EMBED 2048
#define F1D 1024
#define F2D 512
#define NE 120         // edges
#define H1_DIM 480
#define H2_DIM 1920
#define H3_DIM 30720   // 15*2048

// workspace layout (float offsets) — no zero-init needed anywhere
#define OFF_A    0         // 225 (pad 256)
#define OFF_H2   256       // 1920 (pad to 2048) -> 2304
#define OFF_P3   2304      // 32*30720 = 983040 -> 985344   (k2 K-split partials)
#define OFF_P1   985344    // 16*15*1024 = 245760 -> 1231104
#define OFF_P2   1231104   // 16*15*512 = 122880 -> 1353984
#define OFF_X2   1353984   // 7680 -> 1361664
#define OFF_XBAR 1361664   // 512 -> 1362176
#define OFF_CTX  1362176   // 512 -> 1362688

__device__ inline void f4ma(float4& a, float s, const float4& w) {
    a.x += s * w.x; a.y += s * w.y; a.z += s * w.z; a.w += s * w.w;
}
__device__ inline void f4acc(float4& a, const float4& b) {
    a.x += b.x; a.y += b.y; a.z += b.z; a.w += b.w;
}

// ---------------- K1: blocks 0..59: h1 = relu(f@W1+b1), h2 slice; block 60: A_hat ----------------
__global__ void k1_h2(const float* __restrict__ f, const float* __restrict__ W1,
                      const float* __restrict__ b1, const float* __restrict__ W2,
                      const float* __restrict__ b2, const int* __restrict__ edges,
                      float* __restrict__ ws) {
    int tid = threadIdx.x;
    if (blockIdx.x == 60) {
        __shared__ float dinv[NN];
        __shared__ float A[NN * NN];
        if (tid < NN) {
            int deg = 1;  // self loop
            for (int i = 0; i < NE; ++i) deg += (edges[NE + i] == tid) ? 1 : 0;
            dinv[tid] = rsqrtf((float)deg);
        }
        __syncthreads();
        if (tid < NN * NN) {
            int r = tid / NN, c = tid % NN;
            A[tid] = (r == c) ? dinv[r] * dinv[r] : 0.0f;
        }
        __syncthreads();
        if (tid == 0) {
            for (int i = 0; i < NE; ++i) {
                int s = edges[i], d = edges[NE + i];
                A[d * NN + s] += dinv[s] * dinv[d];
            }
        }
        __syncthreads();
        if (tid < NN * NN) ws[OFF_A + tid] = A[tid];
        return;
    }
    __shared__ float h1[H1_DIM];
    __shared__ float4 red[32][8];
    float fr[NN];
#pragma unroll
    for (int k = 0; k < NN; ++k) fr[k] = f[k];
    for (int j = tid; j < H1_DIM; j += 256) {
        float acc = b1[j];
#pragma unroll
        for (int k = 0; k < NN; ++k) acc += fr[k] * W1[k * H1_DIM + j];
        h1[j] = fmaxf(acc, 0.0f);
    }
    __syncthreads();
    int jg = tid & 7, kc = tid >> 3;
    int j = blockIdx.x * 32 + jg * 4;
    float4 acc = make_float4(0.f, 0.f, 0.f, 0.f);
    for (int r = 0; r < 15; ++r) {
        int k = kc * 15 + r;
        float4 w = *(const float4*)(W2 + k * H2_DIM + j);
        f4ma(acc, h1[k], w);
    }
    red[kc][jg] = acc;
    __syncthreads();
    for (int s = 16; s >= 1; s >>= 1) {
        if (kc < s) f4acc(red[kc][jg], red[kc + s][jg]);
        __syncthreads();
    }
    if (kc == 0) {
        float4 b = *(const float4*)(b2 + j);
        float4 v = red[0][jg];
        v.x = fmaxf(v.x + b.x, 0.f); v.y = fmaxf(v.y + b.y, 0.f);
        v.z = fmaxf(v.z + b.z, 0.f); v.w = fmaxf(v.w + b.w, 0.f);
        *(float4*)(ws + OFF_H2 + j) = v;
    }
}

// ---------------- K2: h3 partials = h2 @ W3 (236 MB stream, 8KB contiguous per row-step) ----------------
// grid (15 col-panels of 2048, 32 k-chunks of 60 rows); block 512 threads, no intra-block reduction
__global__ void k2_h3(const float* __restrict__ W3, float* __restrict__ ws) {
    __shared__ float h2l[60];
    int tid = threadIdx.x;
    int cb = blockIdx.x, kc = blockIdx.y;
    int kbase = kc * 60;
    if (tid < 60) h2l[tid] = ws[OFF_H2 + kbase + tid];
    __syncthreads();
    int col = cb * 2048 + tid * 4;
    float4 acc = make_float4(0.f, 0.f, 0.f, 0.f);
    const float* wp = W3 + (size_t)kbase * H3_DIM + col;
#pragma unroll 6
    for (int r = 0; r < 60; ++r) {
        float4 w = *(const float4*)wp;
        f4ma(acc, h2l[r], w);
        wp += (size_t)H3_DIM;
    }
    *(float4*)(ws + OFF_P3 + (size_t)kc * H3_DIM + col) = acc;
}

// ---- generic fused: X = A_hat @ (sumP + bias [relu]) computed in-block, then X @ W -> Pout ----
// grid (OUT/128, IN/ECH); block 256 = 32 f4-groups x 8 k-subgroups
template<int IN, int OUT, int ECH, int NPART, bool BIAS_PER_NODE, bool RELU>
__global__ void k_mmA(const float* __restrict__ P, const float* __restrict__ bias,
                      const float* __restrict__ W, const float* __restrict__ wsA,
                      float* __restrict__ Pout) {
    __shared__ float4 red[8][32][NN];           // 61440 B; head aliases as S
    __shared__ float Xl[NN * ECH];
    __shared__ float Al[NN * NN];
    float* S = (float*)red;                     // S[m*ECH + c]
    int tid = threadIdx.x;
    int e0 = blockIdx.y * ECH;
    for (int i = tid; i < NN * NN; i += 256) Al[i] = wsA[i];
    for (int q = tid; q < NN * ECH; q += 256) {
        int m = q / ECH, c = q - m * ECH;
        float s = BIAS_PER_NODE ? bias[m * IN + e0 + c] : bias[e0 + c];
#pragma unroll
        for (int p = 0; p < NPART; ++p) s += P[(size_t)p * NN * IN + m * IN + e0 + c];
        if (RELU) s = fmaxf(s, 0.f);
        S[q] = s;
    }
    __syncthreads();
    float xtmp[8];  // up to ceil(NN*ECH/256)=8 for ECH=128
    int nq = 0;
    for (int q = tid; q < NN * ECH; q += 256, ++nq) {
        int n = q / ECH, c = q - n * ECH;
        float x = 0.f;
#pragma unroll
        for (int m = 0; m < NN; ++m) x += Al[n * NN + m] * S[m * ECH + c];
        xtmp[nq] = x;
    }
    __syncthreads();   // done reading S before overwriting via Xl? (Xl separate) — sync for S->Xl ordering safety
    nq = 0;
    for (int q = tid; q < NN * ECH; q += 256, ++nq) Xl[q] = xtmp[nq];
    __syncthreads();
    int fg = tid & 31, kt = tid >> 5;
    int f = blockIdx.x * 128 + fg * 4;
    float4 acc[NN];
#pragma unroll
    for (int n = 0; n < NN; ++n) acc[n] = make_float4(0.f, 0.f, 0.f, 0.f);
    const int RPT = ECH / 8;
    for (int r = 0; r < RPT; ++r) {
        int e = kt * RPT + r;
        float4 w = *(const float4*)(W + (size_t)(e0 + e) * OUT + f);
#pragma unroll
        for (int n = 0; n < NN; ++n) f4ma(acc[n], Xl[n * ECH + e], w);
    }
    __syncthreads();   // done with Xl and S; safe to write red
#pragma unroll
    for (int n = 0; n < NN; ++n) red[kt][fg][n] = acc[n];
    __syncthreads();
    for (int s = 4; s >= 1; s >>= 1) {
        if (kt < s) {
#pragma unroll
            for (int n = 0; n < NN; ++n) f4acc(red[kt][fg][n], red[kt + s][fg][n]);
        }
        __syncthreads();
    }
    if (kt == 0) {
#pragma unroll
        for (int n = 0; n < NN; ++n) {
            *(float4*)(Pout + (size_t)blockIdx.y * NN * OUT + n * OUT + f) = red[0][fg][n];
        }
    }
}

// ---------------- K7: X2 = sum P2 + gb2 (no relu); xbar = mean_n X2 ----------------
// grid 8 blocks x 64 cols
__global__ void k7_fin2(const float* __restrict__ gb2, float* __restrict__ ws) {
    __shared__ float S[NN][64];
    int tid = threadIdx.x;
    int f0 = blockIdx.x * 64;
    for (int q = tid; q < NN * 64; q += 256) {
        int n = q >> 6, c = q & 63;
        float s = gb2[f0 + c];
#pragma unroll
        for (int p = 0; p < 16; ++p) s += ws[OFF_P2 + p * (NN * F2D) + n * F2D + f0 + c];
        S[n][c] = s;
        ws[OFF_X2 + n * F2D + f0 + c] = s;
    }
    __syncthreads();
    if (tid < 64) {
        float s = 0.f;
#pragma unroll
        for (int n = 0; n < NN; ++n) s += S[n][tid];
        ws[OFF_XBAR + f0 + tid] = s * (1.0f / 15.0f);
    }
}

// ---------------- K8: ctx = tanh(xbar @ attW) ----------------
__global__ void k8_ctx(const float* __restrict__ attW, float* __restrict__ ws) {
    __shared__ float xb[F2D];
    __shared__ float4 red[64][4];
    int tid = threadIdx.x;
    for (int e = tid; e < F2D; e += 256) xb[e] = ws[OFF_XBAR + e];
    __syncthreads();
    int fg = tid & 3, kt = tid >> 2;
    int f = blockIdx.x * 16 + fg * 4;
    float4 acc = make_float4(0.f, 0.f, 0.f, 0.f);
    for (int r = 0; r < 8; ++r) {
        int e = kt * 8 + r;
        float4 w = *(const float4*)(attW + e * F2D + f);
        f4ma(acc, xb[e], w);
    }
    red[kt][fg] = acc;
    __syncthreads();
    for (int s = 32; s >= 1; s >>= 1) {
        if (kt < s) f4acc(red[kt][fg], red[kt + s][fg]);
        __syncthreads();
    }
    if (kt == 0) {
        float4 v = red[0][fg];
        ws[OFF_CTX + f + 0] = tanhf(v.x);
        ws[OFF_CTX + f + 1] = tanhf(v.y);
        ws[OFF_CTX + f + 2] = tanhf(v.z);
        ws[OFF_CTX + f + 3] = tanhf(v.w);
    }
}

// ---------------- K9: scores, rep, logits, softmax/loss ----------------
__global__ void k9_final(const float* __restrict__ fcW, const float* __restrict__ fcb,
                         const float* __restrict__ target, const float* __restrict__ ws,
                         float* __restrict__ out) {
    __shared__ float x2l[NN * F2D];
    __shared__ float ctxl[F2D];
    __shared__ float scores[16];
    __shared__ float rep[F2D];
    __shared__ float logits[3];
    int tid = threadIdx.x;
    for (int i = tid; i < NN * F2D; i += 256) x2l[i] = ws[OFF_X2 + i];
    for (int i = tid; i < F2D; i += 256) ctxl[i] = ws[OFF_CTX + i];
    __syncthreads();
    {
        int g = tid >> 4, l = tid & 15;
        if (g < NN) {
            float p = 0.f;
            for (int i = 0; i < 32; ++i) {
                int e = l + 16 * i;
                p += x2l[g * F2D + e] * ctxl[e];
            }
            p += __shfl_xor(p, 1); p += __shfl_xor(p, 2);
            p += __shfl_xor(p, 4); p += __shfl_xor(p, 8);
            if (l == 0) scores[g] = 1.0f / (1.0f + expf(-p));
        }
    }
    __syncthreads();
    for (int fi = tid; fi < F2D; fi += 256) {
        float v = 0.f;
#pragma unroll
        for (int n = 0; n < NN; ++n) v += x2l[n * F2D + fi] * scores[n];
        rep[fi] = v;
    }
    __syncthreads();
    if (tid < 192) {
        int j = tid >> 6, l = tid & 63;
        float p = 0.f;
        for (int i = 0; i < 8; ++i) {
            int e = l + 64 * i;
            p += rep[e] * fcW[e * 3 + j];
        }
        p += __shfl_xor(p, 1); p += __shfl_xor(p, 2); p += __shfl_xor(p, 4);
        p += __shfl_xor(p, 8); p += __shfl_xor(p, 16); p += __shfl_xor(p, 32);
        if (l == 0) logits[j] = p + fcb[j];
    }
    __syncthreads();
    if (tid == 0) {
        float t0 = target[0], t1 = target[1], t2 = target[2];
        int cls = 0; float best = t0;
        if (t1 > best) { best = t1; cls = 1; }
        if (t2 > best) { cls = 2; }
        float l0 = logits[0], l1 = logits[1], l2 = logits[2];
        float m = fmaxf(l0, fmaxf(l1, l2));
        float e0 = expf(l0 - m), e1 = expf(l1 - m), e2 = expf(l2 - m);
        float s = e0 + e1 + e2;
        float lc = (cls == 0) ? l0 : ((cls == 1) ? l1 : l2);
        out[0] = -(lc - m - logf(s));
        out[1] = e0 / s; out[2] = e1 / s; out[3] = e2 / s;
    }
}

extern "C" void kernel_launch(void* const* d_in, const int* in_sizes, int n_in,
                              void* d_out, int out_size, void* d_ws, size_t ws_size,
                              hipStream_t stream) {
    const float* f    = (const float*)d_in[0];
    const int*   ei   = (const int*)d_in[1];
    const float* tgt  = (const float*)d_in[2];
    const float* W1   = (const float*)d_in[3];
    const float* b1   = (const float*)d_in[4];
    const float* W2   = (const float*)d_in[5];
    const float* b2   = (const float*)d_in[6];
    const float* W3   = (const float*)d_in[7];
    const float* b3   = (const float*)d_in[8];
    const float* gW1  = (const float*)d_in[9];
    const float* gb1  = (const float*)d_in[10];
    const float* gW2  = (const float*)d_in[11];
    const float* gb2  = (const float*)d_in[12];
    const float* attW = (const float*)d_in[13];
    const float* fcW  = (const float*)d_in[14];
    const float* fcb  = (const float*)d_in[15];
    float* ws  = (float*)d_ws;
    float* out = (float*)d_out;

    k1_h2<<<dim3(61), dim3(256), 0, stream>>>(f, W1, b1, W2, b2, ei, ws);
    k2_h3<<<dim3(15, 32), dim3(512), 0, stream>>>(W3, ws);
    // conv1: Xg1 = A_hat @ (sum P3 + b3);  P1 = Xg1-slices @ gW1   (k3 fused in)
    k_mmA<2048, 1024, 128, 32, true, false>
        <<<dim3(8, 16), dim3(256), 0, stream>>>(ws + OFF_P3, b3, gW1, ws + OFF_A, ws + OFF_P1);
    // conv2: Xg2 = A_hat @ relu(sum P1 + gb1);  P2 = Xg2-slices @ gW2   (k5 fused in)
    k_mmA<1024, 512, 64, 16, false, true>
        <<<dim3(4, 16), dim3(256), 0, stream>>>(ws + OFF_P1, gb1, gW2, ws + OFF_A, ws + OFF_P2);
    k7_fin2<<<dim3(8), dim3(256), 0, stream>>>(gb2, ws);
    k8_ctx<<<dim3(32), dim3(256), 0, stream>>>(attW, ws);
    k9_final<<<dim3(1), dim3(256), 0, stream>>>(fcW, fcb, tgt, ws, out);
}

// Round 4
// 411.518 us; speedup vs baseline: 1.0235x; 1.0235x over previous
//
#include <hip/hip_runtime.h>
#include <math.h>

#define NN 15          // nodes
#define EMBED 2048
#define F1D 1024
#define F2D 512
#define NE 120         // edges
#define H1_DIM 480
#define H2_DIM 1920
#define H3_DIM 30720   // 15*2048

// workspace layout (float offsets) — no zero-init needed anywhere
#define OFF_A    0         // 225 (pad 256)
#define OFF_H2   256       // 1920 (pad to 2048) -> 2304
#define OFF_P3   2304      // 8*30720 = 245760 -> 248064   (k2 K-split partials)
#define OFF_P1   248064    // 16*15*1024 = 245760 -> 493824
#define OFF_P2   493824    // 16*15*512 = 122880 -> 616704
#define OFF_X2   616704    // 7680 -> 624384
#define OFF_XBAR 624384    // 512 -> 624896
#define OFF_CTX  624896    // 512 -> 625408

__device__ inline void f4ma(float4& a, float s, const float4& w) {
    a.x += s * w.x; a.y += s * w.y; a.z += s * w.z; a.w += s * w.w;
}
__device__ inline void f4acc(float4& a, const float4& b) {
    a.x += b.x; a.y += b.y; a.z += b.z; a.w += b.w;
}

// ---------------- K1: blocks 0..59: h1 = relu(f@W1+b1), h2 slice; block 60: A_hat ----------------
__global__ void k1_h2(const float* __restrict__ f, const float* __restrict__ W1,
                      const float* __restrict__ b1, const float* __restrict__ W2,
                      const float* __restrict__ b2, const int* __restrict__ edges,
                      float* __restrict__ ws) {
    int tid = threadIdx.x;
    if (blockIdx.x == 60) {
        __shared__ float dinv[NN];
        __shared__ float A[NN * NN];
        if (tid < NN) {
            int deg = 1;  // self loop
            for (int i = 0; i < NE; ++i) deg += (edges[NE + i] == tid) ? 1 : 0;
            dinv[tid] = rsqrtf((float)deg);
        }
        __syncthreads();
        if (tid < NN * NN) {
            int r = tid / NN, c = tid % NN;
            A[tid] = (r == c) ? dinv[r] * dinv[r] : 0.0f;
        }
        __syncthreads();
        if (tid == 0) {
            for (int i = 0; i < NE; ++i) {
                int s = edges[i], d = edges[NE + i];
                A[d * NN + s] += dinv[s] * dinv[d];
            }
        }
        __syncthreads();
        if (tid < NN * NN) ws[OFF_A + tid] = A[tid];
        return;
    }
    __shared__ float h1[H1_DIM];
    __shared__ float4 red[32][8];
    float fr[NN];
#pragma unroll
    for (int k = 0; k < NN; ++k) fr[k] = f[k];
    for (int j = tid; j < H1_DIM; j += 256) {
        float acc = b1[j];
#pragma unroll
        for (int k = 0; k < NN; ++k) acc += fr[k] * W1[k * H1_DIM + j];
        h1[j] = fmaxf(acc, 0.0f);
    }
    __syncthreads();
    int jg = tid & 7, kc = tid >> 3;
    int j = blockIdx.x * 32 + jg * 4;
    float4 acc = make_float4(0.f, 0.f, 0.f, 0.f);
    for (int r = 0; r < 15; ++r) {
        int k = kc * 15 + r;
        float4 w = *(const float4*)(W2 + k * H2_DIM + j);
        f4ma(acc, h1[k], w);
    }
    red[kc][jg] = acc;
    __syncthreads();
    for (int s = 16; s >= 1; s >>= 1) {
        if (kc < s) f4acc(red[kc][jg], red[kc + s][jg]);
        __syncthreads();
    }
    if (kc == 0) {
        float4 b = *(const float4*)(b2 + j);
        float4 v = red[0][jg];
        v.x = fmaxf(v.x + b.x, 0.f); v.y = fmaxf(v.y + b.y, 0.f);
        v.z = fmaxf(v.z + b.z, 0.f); v.w = fmaxf(v.w + b.w, 0.f);
        *(float4*)(ws + OFF_H2 + j) = v;
    }
}

// ---------------- K2: h3 partials = h2 @ W3 (236 MB stream, 4KB contiguous per row-step) ----------------
// grid (30 col-panels of 1024, 8 k-chunks of 240 rows); block 256, no intra-block K-reduction
__global__ void k2_h3(const float* __restrict__ W3, float* __restrict__ ws) {
    __shared__ float h2l[240];
    int tid = threadIdx.x;
    int cb = blockIdx.x, kc = blockIdx.y;
    int kbase = kc * 240;
    if (tid < 240) h2l[tid] = ws[OFF_H2 + kbase + tid];
    __syncthreads();
    int col = cb * 1024 + tid * 4;
    float4 acc = make_float4(0.f, 0.f, 0.f, 0.f);
    const float* wp = W3 + (size_t)kbase * H3_DIM + col;
#pragma unroll 8
    for (int r = 0; r < 240; ++r) {
        float4 w = *(const float4*)wp;
        f4ma(acc, h2l[r], w);
        wp += (size_t)H3_DIM;
    }
    *(float4*)(ws + OFF_P3 + (size_t)kc * H3_DIM + col) = acc;
}

// ---- generic fused: X = A_hat @ (sumP + bias [relu]) computed in-block, then X @ W -> Pout ----
// grid (OUT/128, IN/ECH); block 256 = 32 f4-groups x 8 k-subgroups
template<int IN, int OUT, int ECH, int NPART, bool BIAS_PER_NODE, bool RELU>
__global__ void k_mmA(const float* __restrict__ P, const float* __restrict__ bias,
                      const float* __restrict__ W, const float* __restrict__ wsA,
                      float* __restrict__ Pout) {
    __shared__ float4 red[8][32][NN];           // 61440 B; head aliases as S
    __shared__ float Xl[NN * ECH];
    __shared__ float Al[NN * NN];
    float* S = (float*)red;                     // S[m*ECH + c]
    int tid = threadIdx.x;
    int e0 = blockIdx.y * ECH;
    for (int i = tid; i < NN * NN; i += 256) Al[i] = wsA[i];
    for (int q = tid; q < NN * ECH; q += 256) {
        int m = q / ECH, c = q - m * ECH;
        float s = BIAS_PER_NODE ? bias[m * IN + e0 + c] : bias[e0 + c];
#pragma unroll
        for (int p = 0; p < NPART; ++p) s += P[(size_t)p * NN * IN + m * IN + e0 + c];
        if (RELU) s = fmaxf(s, 0.f);
        S[q] = s;
    }
    __syncthreads();
    float xtmp[8];  // up to ceil(NN*ECH/256)=8 for ECH=128
    int nq = 0;
    for (int q = tid; q < NN * ECH; q += 256, ++nq) {
        int n = q / ECH, c = q - n * ECH;
        float x = 0.f;
#pragma unroll
        for (int m = 0; m < NN; ++m) x += Al[n * NN + m] * S[m * ECH + c];
        xtmp[nq] = x;
    }
    __syncthreads();
    nq = 0;
    for (int q = tid; q < NN * ECH; q += 256, ++nq) Xl[q] = xtmp[nq];
    __syncthreads();
    int fg = tid & 31, kt = tid >> 5;
    int f = blockIdx.x * 128 + fg * 4;
    float4 acc[NN];
#pragma unroll
    for (int n = 0; n < NN; ++n) acc[n] = make_float4(0.f, 0.f, 0.f, 0.f);
    const int RPT = ECH / 8;
    for (int r = 0; r < RPT; ++r) {
        int e = kt * RPT + r;
        float4 w = *(const float4*)(W + (size_t)(e0 + e) * OUT + f);
#pragma unroll
        for (int n = 0; n < NN; ++n) f4ma(acc[n], Xl[n * ECH + e], w);
    }
    __syncthreads();   // done with Xl and S; safe to overwrite red
#pragma unroll
    for (int n = 0; n < NN; ++n) red[kt][fg][n] = acc[n];
    __syncthreads();
    for (int s = 4; s >= 1; s >>= 1) {
        if (kt < s) {
#pragma unroll
            for (int n = 0; n < NN; ++n) f4acc(red[kt][fg][n], red[kt + s][fg][n]);
        }
        __syncthreads();
    }
    if (kt == 0) {
#pragma unroll
        for (int n = 0; n < NN; ++n) {
            *(float4*)(Pout + (size_t)blockIdx.y * NN * OUT + n * OUT + f) = red[0][fg][n];
        }
    }
}

// ---------------- K7: X2 = sum P2 + gb2 (no relu); xbar = mean_n X2 ----------------
// grid 8 blocks x 64 cols
__global__ void k7_fin2(const float* __restrict__ gb2, float* __restrict__ ws) {
    __shared__ float S[NN][64];
    int tid = threadIdx.x;
    int f0 = blockIdx.x * 64;
    for (int q = tid; q < NN * 64; q += 256) {
        int n = q >> 6, c = q & 63;
        float s = gb2[f0 + c];
#pragma unroll
        for (int p = 0; p < 16; ++p) s += ws[OFF_P2 + p * (NN * F2D) + n * F2D + f0 + c];
        S[n][c] = s;
        ws[OFF_X2 + n * F2D + f0 + c] = s;
    }
    __syncthreads();
    if (tid < 64) {
        float s = 0.f;
#pragma unroll
        for (int n = 0; n < NN; ++n) s += S[n][tid];
        ws[OFF_XBAR + f0 + tid] = s * (1.0f / 15.0f);
    }
}

// ---------------- K8: ctx = tanh(xbar @ attW) ----------------
__global__ void k8_ctx(const float* __restrict__ attW, float* __restrict__ ws) {
    __shared__ float xb[F2D];
    __shared__ float4 red[64][4];
    int tid = threadIdx.x;
    for (int e = tid; e < F2D; e += 256) xb[e] = ws[OFF_XBAR + e];
    __syncthreads();
    int fg = tid & 3, kt = tid >> 2;
    int f = blockIdx.x * 16 + fg * 4;
    float4 acc = make_float4(0.f, 0.f, 0.f, 0.f);
    for (int r = 0; r < 8; ++r) {
        int e = kt * 8 + r;
        float4 w = *(const float4*)(attW + e * F2D + f);
        f4ma(acc, xb[e], w);
    }
    red[kt][fg] = acc;
    __syncthreads();
    for (int s = 32; s >= 1; s >>= 1) {
        if (kt < s) f4acc(red[kt][fg], red[kt + s][fg]);
        __syncthreads();
    }
    if (kt == 0) {
        float4 v = red[0][fg];
        ws[OFF_CTX + f + 0] = tanhf(v.x);
        ws[OFF_CTX + f + 1] = tanhf(v.y);
        ws[OFF_CTX + f + 2] = tanhf(v.z);
        ws[OFF_CTX + f + 3] = tanhf(v.w);
    }
}

// ---------------- K9: scores, rep, logits, softmax/loss ----------------
__global__ void k9_final(const float* __restrict__ fcW, const float* __restrict__ fcb,
                         const float* __restrict__ target, const float* __restrict__ ws,
                         float* __restrict__ out) {
    __shared__ float x2l[NN * F2D];
    __shared__ float ctxl[F2D];
    __shared__ float scores[16];
    __shared__ float rep[F2D];
    __shared__ float logits[3];
    int tid = threadIdx.x;
    for (int i = tid; i < NN * F2D; i += 256) x2l[i] = ws[OFF_X2 + i];
    for (int i = tid; i < F2D; i += 256) ctxl[i] = ws[OFF_CTX + i];
    __syncthreads();
    {
        int g = tid >> 4, l = tid & 15;
        if (g < NN) {
            float p = 0.f;
            for (int i = 0; i < 32; ++i) {
                int e = l + 16 * i;
                p += x2l[g * F2D + e] * ctxl[e];
            }
            p += __shfl_xor(p, 1); p += __shfl_xor(p, 2);
            p += __shfl_xor(p, 4); p += __shfl_xor(p, 8);
            if (l == 0) scores[g] = 1.0f / (1.0f + expf(-p));
        }
    }
    __syncthreads();
    for (int fi = tid; fi < F2D; fi += 256) {
        float v = 0.f;
#pragma unroll
        for (int n = 0; n < NN; ++n) v += x2l[n * F2D + fi] * scores[n];
        rep[fi] = v;
    }
    __syncthreads();
    if (tid < 192) {
        int j = tid >> 6, l = tid & 63;
        float p = 0.f;
        for (int i = 0; i < 8; ++i) {
            int e = l + 64 * i;
            p += rep[e] * fcW[e * 3 + j];
        }
        p += __shfl_xor(p, 1); p += __shfl_xor(p, 2); p += __shfl_xor(p, 4);
        p += __shfl_xor(p, 8); p += __shfl_xor(p, 16); p += __shfl_xor(p, 32);
        if (l == 0) logits[j] = p + fcb[j];
    }
    __syncthreads();
    if (tid == 0) {
        float t0 = target[0], t1 = target[1], t2 = target[2];
        int cls = 0; float best = t0;
        if (t1 > best) { best = t1; cls = 1; }
        if (t2 > best) { cls = 2; }
        float l0 = logits[0], l1 = logits[1], l2 = logits[2];
        float m = fmaxf(l0, fmaxf(l1, l2));
        float e0 = expf(l0 - m), e1 = expf(l1 - m), e2 = expf(l2 - m);
        float s = e0 + e1 + e2;
        float lc = (cls == 0) ? l0 : ((cls == 1) ? l1 : l2);
        out[0] = -(lc - m - logf(s));
        out[1] = e0 / s; out[2] = e1 / s; out[3] = e2 / s;
    }
}

extern "C" void kernel_launch(void* const* d_in, const int* in_sizes, int n_in,
                              void* d_out, int out_size, void* d_ws, size_t ws_size,
                              hipStream_t stream) {
    const float* f    = (const float*)d_in[0];
    const int*   ei   = (const int*)d_in[1];
    const float* tgt  = (const float*)d_in[2];
    const float* W1   = (const float*)d_in[3];
    const float* b1   = (const float*)d_in[4];
    const float* W2   = (const float*)d_in[5];
    const float* b2   = (const float*)d_in[6];
    const float* W3   = (const float*)d_in[7];
    const float* b3   = (const float*)d_in[8];
    const float* gW1  = (const float*)d_in[9];
    const float* gb1  = (const float*)d_in[10];
    const float* gW2  = (const float*)d_in[11];
    const float* gb2  = (const float*)d_in[12];
    const float* attW = (const float*)d_in[13];
    const float* fcW  = (const float*)d_in[14];
    const float* fcb  = (const float*)d_in[15];
    float* ws  = (float*)d_ws;
    float* out = (float*)d_out;

    k1_h2<<<dim3(61), dim3(256), 0, stream>>>(f, W1, b1, W2, b2, ei, ws);
    k2_h3<<<dim3(30, 8), dim3(256), 0, stream>>>(W3, ws);
    // conv1: Xg1 = A_hat @ (sum P3 + b3);  P1 = Xg1-slices @ gW1
    k_mmA<2048, 1024, 128, 8, true, false>
        <<<dim3(8, 16), dim3(256), 0, stream>>>(ws + OFF_P3, b3, gW1, ws + OFF_A, ws + OFF_P1);
    // conv2: Xg2 = A_hat @ relu(sum P1 + gb1);  P2 = Xg2-slices @ gW2
    k_mmA<1024, 512, 64, 16, false, true>
        <<<dim3(4, 16), dim3(256), 0, stream>>>(ws + OFF_P1, gb1, gW2, ws + OFF_A, ws + OFF_P2);
    k7_fin2<<<dim3(8), dim3(256), 0, stream>>>(gb2, ws);
    k8_ctx<<<dim3(32), dim3(256), 0, stream>>>(attW, ws);
    k9_final<<<dim3(1), dim3(256), 0, stream>>>(fcW, fcb, tgt, ws, out);
}